// Round 1
// baseline (24.353 us; speedup 1.0000x reference)
//
#include <hip/hip_runtime.h>

// Problem constants (from reference):
//   B=128, N_FEATURE=512, D=128, MIN_BOUND=-1000, MAX_BOUND=1000, N_BINS=2000
// Key identity: bins is a step function ->
//   y[b,f,d] = prefixW[d, fi] + frac * W[d, fi] + bias[d], relu'd
// where fi = floor(x+1000), frac = (x+1000) - fi.

#define NB   2000
#define DD   128
#define NPAIR (128 * 512)   // B * N_FEATURE

// ---------------------------------------------------------------------------
// Kernel 1: per-d exclusive prefix sum of W[d, :], written TRANSPOSED so the
// eval kernel reads Ct[fi*128 + d] / Wt[fi*128 + d] coalesced across d.
// One wave (64 lanes) per d; each lane owns 32 consecutive bins.
// Row NB (index 2000) holds the full sum (for the pos==2000.0 rounding edge),
// with Wt row NB = 0.
// ---------------------------------------------------------------------------
__global__ __launch_bounds__(64) void scan_kernel(const float* __restrict__ W,
                                                  float* __restrict__ Ct,
                                                  float* __restrict__ Wt) {
    const int d = blockIdx.x;       // 0..127
    const int t = threadIdx.x;      // 0..63
    const float* row = W + (size_t)d * NB;
    const int base = t * 32;        // lane's first bin

    float w[32];
    // vectorized loads: row is 16B-aligned (d*2000*4 bytes, 8000 % 16 == 0),
    // base is a multiple of 32 elements.
    #pragma unroll
    for (int i = 0; i < 32; i += 4) {
        int n = base + i;
        float4 q;
        if (n + 3 < NB) {
            q = *(const float4*)(row + n);
        } else {
            q.x = (n + 0 < NB) ? row[n + 0] : 0.f;
            q.y = (n + 1 < NB) ? row[n + 1] : 0.f;
            q.z = (n + 2 < NB) ? row[n + 2] : 0.f;
            q.w = (n + 3 < NB) ? row[n + 3] : 0.f;
        }
        w[i] = q.x; w[i + 1] = q.y; w[i + 2] = q.z; w[i + 3] = q.w;
    }

    // thread-local exclusive scan
    float v[32];
    float sum = 0.f;
    #pragma unroll
    for (int i = 0; i < 32; i++) { v[i] = sum; sum += w[i]; }

    // wave-wide inclusive scan of the per-lane totals (wave = 64 lanes)
    float inc = sum;
    #pragma unroll
    for (int off = 1; off < 64; off <<= 1) {
        float o = __shfl_up(inc, off);
        if (t >= off) inc += o;
    }
    float excl = inc - sum;   // exclusive prefix of this lane's chunk

    #pragma unroll
    for (int i = 0; i < 32; i++) {
        int n = base + i;
        if (n < NB) {
            Ct[(size_t)n * DD + d] = v[i] + excl;
            Wt[(size_t)n * DD + d] = w[i];
        }
    }
    if (t == 63) {
        Ct[(size_t)NB * DD + d] = inc;  // total sum of the row
        Wt[(size_t)NB * DD + d] = 0.f;
    }
}

// ---------------------------------------------------------------------------
// Kernel 2: out[pair, d] = relu(Ct[fi][d] + frac * Wt[fi][d] + bias[d])
// 256 threads/block: 8 (b,f) pairs per block, 32 lanes x float4 per pair.
// All global accesses are 16B vectorized; out writes are 4KB-contiguous/block.
// ---------------------------------------------------------------------------
__global__ __launch_bounds__(256) void eval_kernel(const float* __restrict__ x,
                                                   const float* __restrict__ bias,
                                                   const float* __restrict__ Ct,
                                                   const float* __restrict__ Wt,
                                                   float* __restrict__ out) {
    const int tid  = threadIdx.x;
    const int lane = tid & 31;       // d-group within pair
    const int slot = tid >> 5;       // 0..7: which pair in this block
    const int d4   = lane * 4;

    const float4 bv = *(const float4*)(bias + d4);

    const int pair = blockIdx.x * 8 + slot;   // 0..65535
    const float xv  = x[pair];
    const float pos = xv + 1000.0f;           // x - MIN_BOUND
    const float fl  = floorf(pos);
    float frac = pos - fl;
    int fi = (int)fl;
    if (fi >= NB) { fi = NB; frac = 0.f; }    // pos rounded up to 2000.0
    if (fi < 0)   { fi = 0;  frac = 0.f; }    // defensive (x >= -1000)

    const float4 c = *(const float4*)(Ct + (size_t)fi * DD + d4);
    const float4 w = *(const float4*)(Wt + (size_t)fi * DD + d4);

    float4 r;
    r.x = fmaxf(fmaf(frac, w.x, c.x) + bv.x, 0.f);
    r.y = fmaxf(fmaf(frac, w.y, c.y) + bv.y, 0.f);
    r.z = fmaxf(fmaf(frac, w.z, c.z) + bv.z, 0.f);
    r.w = fmaxf(fmaf(frac, w.w, c.w) + bv.w, 0.f);

    *(float4*)(out + (size_t)pair * DD + d4) = r;
}

extern "C" void kernel_launch(void* const* d_in, const int* in_sizes, int n_in,
                              void* d_out, int out_size, void* d_ws, size_t ws_size,
                              hipStream_t stream) {
    const float* x    = (const float*)d_in[0];   // [128, 512]
    const float* W    = (const float*)d_in[1];   // [128, 2000]
    const float* bias = (const float*)d_in[2];   // [128]
    float* out = (float*)d_out;                  // [128, 512, 128] f32

    // workspace: Ct[(NB+1) x 128] then Wt[(NB+1) x 128]  (~2.05 MB total)
    float* Ct = (float*)d_ws;
    float* Wt = Ct + (size_t)(NB + 1) * DD;

    hipLaunchKernelGGL(scan_kernel, dim3(DD), dim3(64), 0, stream, W, Ct, Wt);
    hipLaunchKernelGGL(eval_kernel, dim3(NPAIR / 8), dim3(256), 0, stream,
                       x, bias, Ct, Wt, out);
}

// Round 2
// 23.597 us; speedup vs baseline: 1.0320x; 1.0320x over previous
//
#include <hip/hip_runtime.h>

// Problem: y[b,f,d] = relu( prefixW[d, fi] + frac * W[d, fi] + bias[d] )
//   where fi = floor(x+1000), frac = (x+1000) - fi.
//   B=128, F=512, D=128, N_BINS=2000.
//
// Pipeline:
//   S1 chunk_scan : per-d exclusive prefix over 50 chunks of 40 bins -> Pex[50][128]
//   S2 emit       : per-chunk, per-d streaming emit of Ct[n][d] (+bias) and
//                   Wt[n][d], coalesced across d (fixed n = 512B contiguous)
//   E  eval       : out[pair,d] = relu(fma(frac, Wt[fi][d], Ct[fi][d]))
// Row NB (2000) holds the full sum (pos==2000.0 float-rounding edge), Wt=0.

#define NB    2000
#define DD    128
#define CH    50          // chunks
#define CHUNK 40          // bins per chunk  (CH*CHUNK == NB)
#define NPAIR (128 * 512)

// ---------------------------------------------------------------------------
// S1: chunk sums + wave-scan -> exclusive chunk prefixes Pex[c*128 + d]
// ---------------------------------------------------------------------------
__global__ __launch_bounds__(64) void chunk_scan_kernel(const float* __restrict__ W,
                                                        float* __restrict__ Pex) {
    const int d = blockIdx.x;     // 0..127
    const int t = threadIdx.x;    // 0..63 (lanes >= CH idle in loads)

    float s = 0.f;
    if (t < CH) {
        const float* p = W + (size_t)d * NB + t * CHUNK;   // 160B-aligned
        #pragma unroll
        for (int i = 0; i < CHUNK; i += 4) {
            float4 q = *(const float4*)(p + i);
            s += q.x + q.y + q.z + q.w;
        }
    }
    // inclusive wave scan (64 lanes; idle lanes contribute 0)
    float inc = s;
    #pragma unroll
    for (int off = 1; off < 64; off <<= 1) {
        float o = __shfl_up(inc, off);
        if (t >= off) inc += o;
    }
    if (t < CH) Pex[t * DD + d] = inc - s;   // exclusive prefix of chunk t
}

// ---------------------------------------------------------------------------
// S2: emit Ct (with bias folded in) and Wt, coalesced across d.
// Grid: CH blocks x 128 threads (thread = d).
// ---------------------------------------------------------------------------
__global__ __launch_bounds__(128) void emit_kernel(const float* __restrict__ W,
                                                   const float* __restrict__ bias,
                                                   const float* __restrict__ Pex,
                                                   float* __restrict__ Ct,
                                                   float* __restrict__ Wt) {
    const int c = blockIdx.x;     // chunk 0..CH-1
    const int d = threadIdx.x;    // 0..127

    float run = Pex[c * DD + d];  // coalesced
    const float b = bias[d];
    const float* p = W + (size_t)d * NB + c * CHUNK;
    const int nbase = c * CHUNK;

    #pragma unroll
    for (int i = 0; i < CHUNK; i += 4) {
        float4 q = *(const float4*)(p + i);
        int n = nbase + i;
        Ct[(size_t)(n + 0) * DD + d] = run + b;  Wt[(size_t)(n + 0) * DD + d] = q.x;  run += q.x;
        Ct[(size_t)(n + 1) * DD + d] = run + b;  Wt[(size_t)(n + 1) * DD + d] = q.y;  run += q.y;
        Ct[(size_t)(n + 2) * DD + d] = run + b;  Wt[(size_t)(n + 2) * DD + d] = q.z;  run += q.z;
        Ct[(size_t)(n + 3) * DD + d] = run + b;  Wt[(size_t)(n + 3) * DD + d] = q.w;  run += q.w;
    }
    if (c == CH - 1) {            // row NB: full sum (pos rounded to 2000.0)
        Ct[(size_t)NB * DD + d] = run + b;
        Wt[(size_t)NB * DD + d] = 0.f;
    }
}

// ---------------------------------------------------------------------------
// E: out[pair, d] = relu(fma(frac, Wt[fi][d], Ct[fi][d]))
// 256 threads/block: 8 pairs per block, 32 lanes x float4 per pair.
// ---------------------------------------------------------------------------
__global__ __launch_bounds__(256) void eval_kernel(const float* __restrict__ x,
                                                   const float* __restrict__ Ct,
                                                   const float* __restrict__ Wt,
                                                   float* __restrict__ out) {
    const int tid  = threadIdx.x;
    const int lane = tid & 31;
    const int slot = tid >> 5;
    const int d4   = lane * 4;

    const int pair = blockIdx.x * 8 + slot;
    const float pos = x[pair] + 1000.0f;
    const float fl  = floorf(pos);
    float frac = pos - fl;
    int fi = (int)fl;
    if (fi >= NB) { fi = NB; frac = 0.f; }
    if (fi < 0)   { fi = 0;  frac = 0.f; }

    const float4 c = *(const float4*)(Ct + (size_t)fi * DD + d4);
    const float4 w = *(const float4*)(Wt + (size_t)fi * DD + d4);

    float4 r;
    r.x = fmaxf(fmaf(frac, w.x, c.x), 0.f);
    r.y = fmaxf(fmaf(frac, w.y, c.y), 0.f);
    r.z = fmaxf(fmaf(frac, w.z, c.z), 0.f);
    r.w = fmaxf(fmaf(frac, w.w, c.w), 0.f);

    *(float4*)(out + (size_t)pair * DD + d4) = r;
}

extern "C" void kernel_launch(void* const* d_in, const int* in_sizes, int n_in,
                              void* d_out, int out_size, void* d_ws, size_t ws_size,
                              hipStream_t stream) {
    const float* x    = (const float*)d_in[0];   // [128, 512]
    const float* W    = (const float*)d_in[1];   // [128, 2000]
    const float* bias = (const float*)d_in[2];   // [128]
    float* out = (float*)d_out;                  // [128, 512, 128] f32

    float* Ct  = (float*)d_ws;                        // (NB+1) x 128
    float* Wt  = Ct + (size_t)(NB + 1) * DD;          // (NB+1) x 128
    float* Pex = Wt + (size_t)(NB + 1) * DD;          // CH x 128

    hipLaunchKernelGGL(chunk_scan_kernel, dim3(DD), dim3(64), 0, stream, W, Pex);
    hipLaunchKernelGGL(emit_kernel, dim3(CH), dim3(128), 0, stream, W, bias, Pex, Ct, Wt);
    hipLaunchKernelGGL(eval_kernel, dim3(NPAIR / 8), dim3(256), 0, stream,
                       x, Ct, Wt, out);
}

// Round 3
// 21.131 us; speedup vs baseline: 1.1525x; 1.1167x over previous
//
#include <hip/hip_runtime.h>

// y[b,f,d] = relu( prefixW[d, fi] + frac * W[d, fi] + bias[d] ),
//   fi = floor(x+1000), frac = (x+1000) - fi.
//   B=128, F=512, D=128, N_BINS=2000.
//
// Tables in ws, layout [n][d] (coalesced across d):
//   Ct[n][d] = sum_{k<n} W[d,k] + bias[d]    (bias folded in)
//   Wt[n][d] = W[d,n]
// Row NB=2000 holds full sum (pos==2000.0 float-rounding edge), Wt=0.
//
// K1 chunk_scan: 128 blocks (one per d) x 256 thr; thread c sums its 8-bin
//                chunk, block-wide scan -> Pex[250][128].
// K2 emit      : 250 blocks (one per chunk) x 128 thr (one per d); stores
//                coalesced across d.
// K3 eval      : 4096 blocks x 256 thr, 16 pairs/block, nontemporal f4 out
//                stores (out is write-once; keep L2 for the Ct/Wt gathers).

#define NB    2000
#define DD    128
#define CHUNK 8
#define CH    250          // CH*CHUNK == NB
#define NPAIR (128 * 512)

typedef float f4 __attribute__((ext_vector_type(4)));

// ---------------------------------------------------------------------------
__global__ __launch_bounds__(256) void chunk_scan_kernel(const float* __restrict__ W,
                                                         float* __restrict__ Pex) {
    const int d = blockIdx.x;      // 0..127
    const int t = threadIdx.x;     // chunk id; 0..249 active

    float s = 0.f;
    if (t < CH) {
        const f4* p = (const f4*)(W + (size_t)d * NB + t * CHUNK);
        f4 a = p[0], b = p[1];
        s = ((a.x + a.y) + (a.z + a.w)) + ((b.x + b.y) + (b.z + b.w));
    }

    // wave-level inclusive scan (64 lanes)
    float inc = s;
    #pragma unroll
    for (int off = 1; off < 64; off <<= 1) {
        float o = __shfl_up(inc, off);
        if ((t & 63) >= off) inc += o;
    }

    // block-level: add totals of preceding waves
    __shared__ float wtot[4];
    const int w = t >> 6, l = t & 63;
    if (l == 63) wtot[w] = inc;
    __syncthreads();
    float add = 0.f;
    #pragma unroll
    for (int k = 0; k < 3; k++)
        if (k < w) add += wtot[k];

    if (t < CH) Pex[t * DD + d] = (inc - s) + add;   // exclusive prefix
}

// ---------------------------------------------------------------------------
__global__ __launch_bounds__(128) void emit_kernel(const float* __restrict__ W,
                                                   const float* __restrict__ bias,
                                                   const float* __restrict__ Pex,
                                                   float* __restrict__ Ct,
                                                   float* __restrict__ Wt) {
    const int c = blockIdx.x;      // 0..249
    const int d = threadIdx.x;     // 0..127

    float run = Pex[c * DD + d] + bias[d];   // bias folded into Ct
    const float* p = W + (size_t)d * NB + c * CHUNK;
    f4 a = *(const f4*)(p);
    f4 b = *(const f4*)(p + 4);
    const float wv[CHUNK] = {a.x, a.y, a.z, a.w, b.x, b.y, b.z, b.w};

    const int nbase = c * CHUNK;
    #pragma unroll
    for (int i = 0; i < CHUNK; i++) {
        Ct[(size_t)(nbase + i) * DD + d] = run;      // 512B contiguous per i
        Wt[(size_t)(nbase + i) * DD + d] = wv[i];
        run += wv[i];
    }
    if (c == CH - 1) {             // row NB: full sum (pos rounded to 2000.0)
        Ct[(size_t)NB * DD + d] = run;
        Wt[(size_t)NB * DD + d] = 0.f;
    }
}

// ---------------------------------------------------------------------------
__global__ __launch_bounds__(256) void eval_kernel(const float* __restrict__ x,
                                                   const float* __restrict__ Ct,
                                                   const float* __restrict__ Wt,
                                                   float* __restrict__ out) {
    const int tid  = threadIdx.x;
    const int lane = tid & 31;      // 32 lanes x f4 cover d=0..127
    const int slot = tid >> 5;      // 0..7
    const int d4   = lane * 4;
    const int base = blockIdx.x * 16;

    #pragma unroll
    for (int h = 0; h < 2; h++) {
        const int pair = base + slot + h * 8;
        const float pos = x[pair] + 1000.0f;
        const float fl  = floorf(pos);
        float frac = pos - fl;
        int fi = (int)fl;
        if (fi >= NB) { fi = NB; frac = 0.f; }
        if (fi < 0)   { fi = 0;  frac = 0.f; }

        const f4 c = *(const f4*)(Ct + (size_t)fi * DD + d4);
        const f4 w = *(const f4*)(Wt + (size_t)fi * DD + d4);

        f4 r;
        r.x = fmaxf(fmaf(frac, w.x, c.x), 0.f);
        r.y = fmaxf(fmaf(frac, w.y, c.y), 0.f);
        r.z = fmaxf(fmaf(frac, w.z, c.z), 0.f);
        r.w = fmaxf(fmaf(frac, w.w, c.w), 0.f);

        // write-once output: bypass L2 allocate so Ct/Wt stay resident
        __builtin_nontemporal_store(r, (f4*)(out + (size_t)pair * DD + d4));
    }
}

extern "C" void kernel_launch(void* const* d_in, const int* in_sizes, int n_in,
                              void* d_out, int out_size, void* d_ws, size_t ws_size,
                              hipStream_t stream) {
    const float* x    = (const float*)d_in[0];   // [128, 512]
    const float* W    = (const float*)d_in[1];   // [128, 2000]
    const float* bias = (const float*)d_in[2];   // [128]
    float* out = (float*)d_out;                  // [128, 512, 128] f32

    float* Ct  = (float*)d_ws;                        // (NB+1) x 128
    float* Wt  = Ct + (size_t)(NB + 1) * DD;          // (NB+1) x 128
    float* Pex = Wt + (size_t)(NB + 1) * DD;          // CH x 128

    hipLaunchKernelGGL(chunk_scan_kernel, dim3(DD), dim3(256), 0, stream, W, Pex);
    hipLaunchKernelGGL(emit_kernel, dim3(CH), dim3(128), 0, stream, W, bias, Pex, Ct, Wt);
    hipLaunchKernelGGL(eval_kernel, dim3(NPAIR / 16), dim3(256), 0, stream,
                       x, Ct, Wt, out);
}